// Round 6
// baseline (996.037 us; speedup 1.0000x reference)
//
#include <hip/hip_runtime.h>
#include <math.h>

// ---------------------------------------------------------------------------
// PiT: encoder lift -> down pos-att -> 4x (pos-att + MLP + residual) -> up
// pos-att -> decoder. Sparse attention via exact percentile selection
// (register-resident windowed histogram + counting selection), fused PV.
// ---------------------------------------------------------------------------

__device__ __forceinline__ float gelu_f(float x) {
  float x3 = x * x * x;
  float inner = x + 0.044715f * x3;
  float t = tanhf(0.7978845608028654f * inner);
  return x * (0.5f * (1.0f + t));
}

// ---------------- encoder lift: out[m][o] = gelu(x[m]·w[o] + b[o]), K=3 -----
__global__ __launch_bounds__(256) void k_lift(const float* __restrict__ x,
                                              const float* __restrict__ w,
                                              const float* __restrict__ b,
                                              float* __restrict__ out) {
  int gid = blockIdx.x * 256 + threadIdx.x;
  int m = gid >> 8, o = gid & 255;
  float a0 = x[m * 3 + 0], a1 = x[m * 3 + 1], a2 = x[m * 3 + 2];
  float acc = a0 * w[o * 3 + 0] + a1 * w[o * 3 + 1] + a2 * w[o * 3 + 2] + b[o];
  out[gid] = gelu_f(acc);
}

// ---------------- dense linear: C = act(A @ W^T + bias [+ D]) ---------------
template <int WL, int ACT, int ADDRES>
__global__ __launch_bounds__(256) void k_linear(const float* __restrict__ A,
                                                const float* __restrict__ W,
                                                const float* __restrict__ bias,
                                                const float* __restrict__ D,
                                                float* __restrict__ C, int M) {
  __shared__ __align__(16) float Al[32][68];
  __shared__ __align__(16) float Wl[32][68];
  int t = threadIdx.x;
  int m0 = blockIdx.x * 64, o0 = blockIdx.y * 64;
  int tr = t >> 4, tc = t & 15;
  float acc[4][4] = {{0.0f}};
  for (int kb = 0; kb < 256; kb += 32) {
#pragma unroll
    for (int e = 0; e < 2; ++e) {
      int idx = t + 256 * e;
      int m = idx >> 3;
      int kq = idx & 7;
      float4 v = *(const float4*)(A + (size_t)(m0 + m) * 256 + kb + kq * 4);
      Al[kq * 4 + 0][m] = v.x; Al[kq * 4 + 1][m] = v.y;
      Al[kq * 4 + 2][m] = v.z; Al[kq * 4 + 3][m] = v.w;
    }
    if (WL == 0) {
#pragma unroll
      for (int e = 0; e < 2; ++e) {
        int idx = t + 256 * e;
        int o = idx >> 3;
        int kq = idx & 7;
        float4 v = *(const float4*)(W + (size_t)(o0 + o) * 256 + kb + kq * 4);
        Wl[kq * 4 + 0][o] = v.x; Wl[kq * 4 + 1][o] = v.y;
        Wl[kq * 4 + 2][o] = v.z; Wl[kq * 4 + 3][o] = v.w;
      }
    } else {
#pragma unroll
      for (int e = 0; e < 8; ++e) {
        int idx = t + 256 * e;
        int k = idx >> 6, o = idx & 63;
        int cc = o0 + o;
        Wl[k][o] = W[(size_t)(cc >> 5) * 8192 + (size_t)(kb + k) * 32 + (cc & 31)];
      }
    }
    __syncthreads();
#pragma unroll
    for (int kk = 0; kk < 32; ++kk) {
      float4 av = *(const float4*)&Al[kk][tr * 4];
      float4 wv = *(const float4*)&Wl[kk][tc * 4];
      float aa[4] = {av.x, av.y, av.z, av.w};
      float ww[4] = {wv.x, wv.y, wv.z, wv.w};
#pragma unroll
      for (int i = 0; i < 4; i++)
#pragma unroll
        for (int jx = 0; jx < 4; jx++)
          acc[i][jx] = fmaf(aa[i], ww[jx], acc[i][jx]);
    }
    __syncthreads();
  }
#pragma unroll
  for (int i = 0; i < 4; i++) {
    int m = m0 + tr * 4 + i;
#pragma unroll
    for (int jx = 0; jx < 4; jx++) {
      int o = o0 + tc * 4 + jx;
      float v = acc[i][jx];
      if (bias) v += bias[o];
      if (ADDRES) v += D[(size_t)m * 256 + o];
      if (ACT) v = gelu_f(v);
      C[(size_t)m * 256 + o] = v;
    }
  }
}

// ---------------- precompute the 48 attention scales ------------------------
__global__ void k_scales(const float* __restrict__ down_r,
                         const float* __restrict__ pa_r,
                         const float* __restrict__ up_r,
                         float* __restrict__ scales) {
  int t = threadIdx.x;
  if (t >= 48) return;
  float rv;
  if (t < 8) rv = down_r[t];
  else if (t < 40) rv = pa_r[t - 8];
  else rv = up_r[t - 40];
  double rd = (double)rv;
  float s1 = (float)sin(rd);
  float u = 1.0f + s1;
  float vc = (float)(0.7853981633974483 * (1.0 - 1e-7));
  float wf = vc * u;
  scales[t] = (float)tan((double)wf);
}

// ---------------- fused select + softmax + PV, register-resident ------------
// Row lives in registers (NPT/thread). Order stats k_lo,k_lo+1 via windowed
// 256-bin histogram (exact recount each attempt; widen/refine loops make it
// correct for any data). Threshold & softmax on f32-rounded products =
// reference-exact semantics.
template <int N>
__global__ __launch_bounds__(256) void k_selpv2(
    const float* __restrict__ mdist, const float* __restrict__ scales,
    int sc_off, int Nq, int k_lo, float hw, float lw, float frac,
    const float* __restrict__ V, int Nk, float* __restrict__ out) {
  constexpr int NPT = N / 256;
  constexpr int NV4 = NPT / 4;
  constexpr int KCAP = 192;
  __shared__ int hist[256];
  __shared__ float sredf[8];
  __shared__ int swoff[4];
  __shared__ int sbinlo, sbinhi, sibase, sincl, sgc;
  __shared__ float scand[128];
  __shared__ float svsel[2];
  __shared__ int kil[KCAP];
  __shared__ float kvw[KCAP];
  __shared__ float pacc[128];

  int row = blockIdx.x;
  int t = threadIdx.x;
  int wid = t >> 6, lane = t & 63;
  int h = row / Nq, j = row - h * Nq;
  float scale = scales[sc_off + h];
  const float* mrow = mdist + (size_t)row * N;

  // ---- load row into registers, track min/max ----
  float rv[NPT];
  float lmin = INFINITY, lmax = -INFINITY;
#pragma unroll
  for (int e = 0; e < NV4; ++e) {
    float4 v = ((const float4*)mrow)[t + 256 * e];
    rv[4 * e + 0] = v.x; rv[4 * e + 1] = v.y;
    rv[4 * e + 2] = v.z; rv[4 * e + 3] = v.w;
    lmin = fminf(lmin, fminf(fminf(v.x, v.y), fminf(v.z, v.w)));
    lmax = fmaxf(lmax, fmaxf(fmaxf(v.x, v.y), fmaxf(v.z, v.w)));
  }
#pragma unroll
  for (int off = 32; off > 0; off >>= 1) {
    lmin = fminf(lmin, __shfl_xor(lmin, off));
    lmax = fmaxf(lmax, __shfl_xor(lmax, off));
  }
  if (lane == 0) { sredf[wid] = lmin; sredf[4 + wid] = lmax; }
  __syncthreads();
  float rmin = fminf(fminf(sredf[0], sredf[1]), fminf(sredf[2], sredf[3]));
  float rmax = fmaxf(fmaxf(sredf[4], sredf[5]), fmaxf(sredf[6], sredf[7]));

  float v_lo = rmin, v_hi = rmin;  // fallback (degenerate all-equal row)
  if (rmax > rmin) {
    float range = rmax - rmin;
    float margin = fmaxf(fabsf(rmax) * 1e-6f, 1e-30f);
    float rtop = rmax + margin;
    float rlo = rmin;
    float rhi = rmin + range * frac;  // expected window covers rank k_lo+1
    if (!(rhi > rlo)) rhi = rtop;
    int below = 0;
    bool need_below = false;
    for (int it = 0; it < 16; ++it) {
      if (need_below) {
        int lb = 0;
#pragma unroll
        for (int e = 0; e < NPT; ++e) lb += (rv[e] < rlo) ? 1 : 0;
#pragma unroll
        for (int off = 32; off > 0; off >>= 1) lb += __shfl_xor(lb, off);
        if (lane == 0) swoff[wid] = lb;
      }
      hist[t] = 0;
      __syncthreads();
      if (need_below) below = swoff[0] + swoff[1] + swoff[2] + swoff[3];
      need_below = false;
      float width = rhi - rlo;
      float sinv = 256.0f / width;
#pragma unroll
      for (int e = 0; e < NPT; ++e) {
        float v = rv[e];
        if (v >= rlo && v < rhi) {
          int b = (int)((v - rlo) * sinv);
          b = b < 0 ? 0 : (b > 255 ? 255 : b);
          atomicAdd(&hist[b], 1);
        }
      }
      __syncthreads();
      int c = hist[t];
      int x = c;
#pragma unroll
      for (int off = 1; off < 64; off <<= 1) {
        int y = __shfl_up(x, off);
        if (lane >= off) x += y;
      }
      if (lane == 63) swoff[wid] = x;
      __syncthreads();
      int wo = 0;
#pragma unroll
      for (int w = 0; w < 4; ++w) wo += (w < wid) ? swoff[w] : 0;
      int incl = x + wo, excl = incl - c;
      int tot = swoff[0] + swoff[1] + swoff[2] + swoff[3];
      int r = k_lo - below;
      if (tot < r + 2) {  // window missed rank k_lo+1: widen (uniform branch)
        rhi = fminf(rlo + width * 8.0f, rtop);
        __syncthreads();
        continue;
      }
      if (excl <= r && r < incl) { sbinlo = t; sibase = excl; }
      if (excl <= r + 1 && r + 1 < incl) { sbinhi = t; sincl = incl; }
      if (t == 0) sgc = 0;
      __syncthreads();
      int b_lo = sbinlo, b_hi = sbinhi;
      int base = sibase;
      int gcount = sincl - base;
      if (gcount <= 128) {
#pragma unroll
        for (int e = 0; e < NPT; ++e) {
          float v = rv[e];
          if (v >= rlo && v < rhi) {
            int b = (int)((v - rlo) * sinv);
            b = b < 0 ? 0 : (b > 255 ? 255 : b);
            if (b >= b_lo && b <= b_hi) {
              int p = atomicAdd(&sgc, 1);
              if (p < 128) scand[p] = v;
            }
          }
        }
        __syncthreads();
        int rr = r - base;
        if (t < gcount) {
          float xv = scand[t];
          int clt = 0, ceq = 0;
          for (int jj = 0; jj < gcount; ++jj) {
            float y = scand[jj];
            clt += (y < xv) ? 1 : 0;
            ceq += (y == xv) ? 1 : 0;
          }
          if (clt <= rr && rr < clt + ceq) svsel[0] = xv;
          if (clt <= rr + 1 && rr + 1 < clt + ceq) svsel[1] = xv;
        }
        __syncthreads();
        v_lo = svsel[0];
        v_hi = svsel[1];
        break;
      }
      // refine to the two target bins (conservative half-bin margins)
      float w256 = width * (1.0f / 256.0f);
      float nlo = rlo + ((float)b_lo - 0.5f) * w256;
      float nhi = rlo + ((float)b_hi + 1.5f) * w256;
      rlo = fmaxf(rlo, nlo);
      rhi = fminf(rhi, nhi);
      need_below = true;
      __syncthreads();
    }
  }

  // ---- threshold on rounded products (reference-exact formula) ----
  float vlos = __fmul_rn(v_lo, scale);
  float vhis = __fmul_rn(v_hi, scale);
  float thr = __fadd_rn(__fmul_rn(vlos, lw), __fmul_rn(vhis, hw));
  float rmins = __fmul_rn(rmin, scale);

  // ---- kept mask from registers + deterministic compaction ----
  int kmask = 0, myc = 0;
#pragma unroll
  for (int e = 0; e < NPT; ++e) {
    if (__fmul_rn(rv[e], scale) <= thr) { kmask |= (1 << e); myc++; }
  }
  int xs = myc;
#pragma unroll
  for (int off = 1; off < 64; off <<= 1) {
    int y = __shfl_up(xs, off);
    if (lane >= off) xs += y;
  }
  if (lane == 63) swoff[wid] = xs;
  __syncthreads();
  int wo2 = 0;
#pragma unroll
  for (int w = 0; w < 4; ++w) wo2 += (w < wid) ? swoff[w] : 0;
  int p = wo2 + xs - myc;
  int K = swoff[0] + swoff[1] + swoff[2] + swoff[3];
  if (K > KCAP) K = KCAP;
#pragma unroll
  for (int e = 0; e < NPT; ++e) {
    if ((kmask >> e) & 1) {
      if (p < KCAP) {
        kil[p] = 4 * t + 1024 * (e >> 2) + (e & 3);
        kvw[p] = rv[e];
      }
      p++;
    }
  }
  __syncthreads();

  // ---- softmax weights on the K-sized compact list ----
  float e0 = 0.0f;
  if (t < K) e0 = expf(__fsub_rn(rmins, __fmul_rn(kvw[t], scale)));
  float es = e0;
#pragma unroll
  for (int off = 32; off > 0; off >>= 1) es += __shfl_xor(es, off);
  if (lane == 0) sredf[wid] = es;
  __syncthreads();
  float total = (sredf[0] + sredf[1]) + (sredf[2] + sredf[3]);
  if (t < K) kvw[t] = e0 / total;
  __syncthreads();

  // ---- PV gather: out[b][j][h*32+c] = gelu(sum_e w_e V[b][n_e][h*32+c]) ----
  int half = t >> 7, b = (t >> 5) & 3, c = t & 31;
  int hcol = h * 32 + c;
  float acc = 0.0f;
  for (int e = half; e < K; e += 2)
    acc = fmaf(kvw[e], V[((size_t)b * Nk + kil[e]) * 256 + hcol], acc);
  if (half) pacc[t - 128] = acc;
  __syncthreads();
  if (!half) {
    float r2 = acc + pacc[t];
    out[((size_t)b * Nq + j) * 256 + hcol] = gelu_f(r2);
  }
}

// ---------------- final 256->1 projection -----------------------------------
__global__ __launch_bounds__(256) void k_de2(const float* __restrict__ A,
                                             const float* __restrict__ w,
                                             const float* __restrict__ b,
                                             float* __restrict__ out) {
  int t = threadIdx.x;
  int row = blockIdx.x * 4 + (t >> 6);
  int lane = t & 63;
  const float* ar = A + (size_t)row * 256;
  float s = 0.0f;
  for (int i = lane; i < 256; i += 64) s = fmaf(ar[i], w[i], s);
#pragma unroll
  for (int off = 32; off > 0; off >>= 1) s += __shfl_down(s, off);
  if (lane == 0) out[row] = s + b[0];
}

// ---------------------------------------------------------------------------
struct SelParams { int k_lo; float hw, lw, frac; };
static SelParams sel_params(double q, int N) {
  SelParams p;
  float idx_q = (float)(q / 100.0);
  float pos = idx_q * (float)(N - 1);
  float lo = floorf(pos);
  p.k_lo = (int)lo;
  p.hw = pos - lo;
  p.lw = 1.0f - p.hw;
  float need = (float)(p.k_lo + 1);
  p.frac = (need + 6.0f * sqrtf(need) + 8.0f) / (float)N;
  return p;
}

extern "C" void kernel_launch(void* const* d_in, const int* in_sizes, int n_in,
                              void* d_out, int out_size, void* d_ws, size_t ws_size,
                              hipStream_t stream) {
  const float* x      = (const float*)d_in[0];
  const float* mdd    = (const float*)d_in[1];
  const float* mdb    = (const float*)d_in[2];
  const float* mdu    = (const float*)d_in[3];
  const float* en_w   = (const float*)d_in[4];
  const float* en_b   = (const float*)d_in[5];
  const float* down_r = (const float*)d_in[6];
  const float* down_w = (const float*)d_in[7];
  const float* pa_r   = (const float*)d_in[8];
  const float* pa_w   = (const float*)d_in[9];
  const float* mlp1_w = (const float*)d_in[10];
  const float* mlp1_b = (const float*)d_in[11];
  const float* mlp2_w = (const float*)d_in[12];
  const float* mlp2_b = (const float*)d_in[13];
  const float* res_w  = (const float*)d_in[14];
  const float* res_b  = (const float*)d_in[15];
  const float* up_r   = (const float*)d_in[16];
  const float* up_w   = (const float*)d_in[17];
  const float* de1_w  = (const float*)d_in[18];
  const float* de1_b  = (const float*)d_in[19];
  const float* de2_w  = (const float*)d_in[20];
  const float* de2_b  = (const float*)d_in[21];
  float* out = (float*)d_out;
  float* ws = (float*)d_ws;

  // ws layout (floats)
  float* hfull = ws;                     // 4194304
  float* val   = ws + 4194304;           // 4194304
  float* paout = ws + 8388608;           // 4194304
  float* hlat  = ws + 12582912;          // 1048576
  float* t1    = ws + 13631488;          // 1048576
  float* t2    = ws + 14680064;          // 1048576
  float* scales = ws + 15728640;         // 48

  k_scales<<<1, 64, 0, stream>>>(down_r, pa_r, up_r, scales);

  // encoder
  k_lift<<<16384, 256, 0, stream>>>(x, en_w, en_b, hfull);

  // down stage (H=8, Nq=1024, Nk=4096, q=3 -> keep ~123)
  SelParams pd = sel_params(3.0, 4096);
  k_linear<1, 0, 0><<<dim3(256, 4), 256, 0, stream>>>(hfull, down_w, nullptr, nullptr, val, 16384);
  k_selpv2<4096><<<8192, 256, 0, stream>>>(mdd, scales, 0, 1024, pd.k_lo, pd.hw, pd.lw, pd.frac, val, 4096, hlat);

  // processor blocks (Nq=Nk=1024, q=5 -> keep ~52)
  SelParams pb = sel_params(5.0, 1024);
  for (int i = 0; i < 4; i++) {
    k_linear<1, 0, 0><<<dim3(64, 4), 256, 0, stream>>>(hlat, pa_w + (size_t)i * 65536, nullptr, nullptr, val, 4096);
    k_selpv2<1024><<<8192, 256, 0, stream>>>(mdb + (size_t)i * 8388608, scales, 8 + i * 8, 1024, pb.k_lo, pb.hw, pb.lw, pb.frac, val, 1024, paout);
    k_linear<0, 1, 0><<<dim3(64, 4), 256, 0, stream>>>(paout, mlp1_w + (size_t)i * 65536, mlp1_b + i * 256, nullptr, t1, 4096);
    k_linear<0, 0, 0><<<dim3(64, 4), 256, 0, stream>>>(hlat, res_w + (size_t)i * 65536, res_b + i * 256, nullptr, t2, 4096);
    k_linear<0, 1, 1><<<dim3(64, 4), 256, 0, stream>>>(t1, mlp2_w + (size_t)i * 65536, mlp2_b + i * 256, t2, hlat, 4096);
  }

  // up stage (H=8, Nq=4096, Nk=1024, q=3 -> keep ~31)
  SelParams pu = sel_params(3.0, 1024);
  k_linear<1, 0, 0><<<dim3(64, 4), 256, 0, stream>>>(hlat, up_w, nullptr, nullptr, val, 4096);
  k_selpv2<1024><<<32768, 256, 0, stream>>>(mdu, scales, 40, 4096, pu.k_lo, pu.hw, pu.lw, pu.frac, val, 1024, paout);

  // decoder
  k_linear<0, 1, 0><<<dim3(256, 4), 256, 0, stream>>>(paout, de1_w, de1_b, nullptr, hfull, 16384);
  k_de2<<<4096, 256, 0, stream>>>(hfull, de2_w, de2_b, out);
}

// Round 7
// 822.050 us; speedup vs baseline: 1.2116x; 1.2116x over previous
//
#include <hip/hip_runtime.h>
#include <math.h>

// ---------------------------------------------------------------------------
// PiT: encoder lift -> down pos-att -> 4x (pos-att + MLP + residual) -> up
// pos-att -> decoder. Sparse attention: wave-per-row (zero barriers) window
// filter + counting selection for exact percentile, fused softmax+PV.
// ---------------------------------------------------------------------------

__device__ __forceinline__ float gelu_f(float x) {
  float x3 = x * x * x;
  float inner = x + 0.044715f * x3;
  float t = tanhf(0.7978845608028654f * inner);
  return x * (0.5f * (1.0f + t));
}

// ---------------- encoder lift: out[m][o] = gelu(x[m]·w[o] + b[o]), K=3 -----
__global__ __launch_bounds__(256) void k_lift(const float* __restrict__ x,
                                              const float* __restrict__ w,
                                              const float* __restrict__ b,
                                              float* __restrict__ out) {
  int gid = blockIdx.x * 256 + threadIdx.x;
  int m = gid >> 8, o = gid & 255;
  float a0 = x[m * 3 + 0], a1 = x[m * 3 + 1], a2 = x[m * 3 + 2];
  float acc = a0 * w[o * 3 + 0] + a1 * w[o * 3 + 1] + a2 * w[o * 3 + 2] + b[o];
  out[gid] = gelu_f(acc);
}

// ---------------- dense linear: C = act(A @ W^T + bias [+ D]) ---------------
template <int WL, int ACT, int ADDRES>
__global__ __launch_bounds__(256) void k_linear(const float* __restrict__ A,
                                                const float* __restrict__ W,
                                                const float* __restrict__ bias,
                                                const float* __restrict__ D,
                                                float* __restrict__ C, int M) {
  __shared__ __align__(16) float Al[32][68];
  __shared__ __align__(16) float Wl[32][68];
  int t = threadIdx.x;
  int m0 = blockIdx.x * 64, o0 = blockIdx.y * 64;
  int tr = t >> 4, tc = t & 15;
  float acc[4][4] = {{0.0f}};
  for (int kb = 0; kb < 256; kb += 32) {
#pragma unroll
    for (int e = 0; e < 2; ++e) {
      int idx = t + 256 * e;
      int m = idx >> 3;
      int kq = idx & 7;
      float4 v = *(const float4*)(A + (size_t)(m0 + m) * 256 + kb + kq * 4);
      Al[kq * 4 + 0][m] = v.x; Al[kq * 4 + 1][m] = v.y;
      Al[kq * 4 + 2][m] = v.z; Al[kq * 4 + 3][m] = v.w;
    }
    if (WL == 0) {
#pragma unroll
      for (int e = 0; e < 2; ++e) {
        int idx = t + 256 * e;
        int o = idx >> 3;
        int kq = idx & 7;
        float4 v = *(const float4*)(W + (size_t)(o0 + o) * 256 + kb + kq * 4);
        Wl[kq * 4 + 0][o] = v.x; Wl[kq * 4 + 1][o] = v.y;
        Wl[kq * 4 + 2][o] = v.z; Wl[kq * 4 + 3][o] = v.w;
      }
    } else {
#pragma unroll
      for (int e = 0; e < 8; ++e) {
        int idx = t + 256 * e;
        int k = idx >> 6, o = idx & 63;
        int cc = o0 + o;
        Wl[k][o] = W[(size_t)(cc >> 5) * 8192 + (size_t)(kb + k) * 32 + (cc & 31)];
      }
    }
    __syncthreads();
#pragma unroll
    for (int kk = 0; kk < 32; ++kk) {
      float4 av = *(const float4*)&Al[kk][tr * 4];
      float4 wv = *(const float4*)&Wl[kk][tc * 4];
      float aa[4] = {av.x, av.y, av.z, av.w};
      float ww[4] = {wv.x, wv.y, wv.z, wv.w};
#pragma unroll
      for (int i = 0; i < 4; i++)
#pragma unroll
        for (int jx = 0; jx < 4; jx++)
          acc[i][jx] = fmaf(aa[i], ww[jx], acc[i][jx]);
    }
    __syncthreads();
  }
#pragma unroll
  for (int i = 0; i < 4; i++) {
    int m = m0 + tr * 4 + i;
#pragma unroll
    for (int jx = 0; jx < 4; jx++) {
      int o = o0 + tc * 4 + jx;
      float v = acc[i][jx];
      if (bias) v += bias[o];
      if (ADDRES) v += D[(size_t)m * 256 + o];
      if (ACT) v = gelu_f(v);
      C[(size_t)m * 256 + o] = v;
    }
  }
}

// ---------------- precompute the 48 attention scales ------------------------
__global__ void k_scales(const float* __restrict__ down_r,
                         const float* __restrict__ pa_r,
                         const float* __restrict__ up_r,
                         float* __restrict__ scales) {
  int t = threadIdx.x;
  if (t >= 48) return;
  float rv;
  if (t < 8) rv = down_r[t];
  else if (t < 40) rv = pa_r[t - 8];
  else rv = up_r[t - 40];
  double rd = (double)rv;
  float s1 = (float)sin(rd);
  float u = 1.0f + s1;
  float vc = (float)(0.7853981633974483 * (1.0 - 1e-7));
  float wf = vc * u;
  scales[t] = (float)tan((double)wf);
}

// ---------------- wave-per-row fused select + softmax + PV ------------------
// One 64-lane wave per (h, q-row). No __syncthreads: per-wave LDS slices only
// (LDS ops within a wave execute in order). Window filter -> candidates in
// LDS; exact ranks k_lo,k_lo+1 via counting selection over candidates (raw
// domain: valid since scale>0 and rn is monotone); threshold on f32-rounded
// products = reference-exact. Kept set is guaranteed a subset of candidates
// by the rn(wtop*scale)>thr guard (retry otherwise).
template <int N, int CAP>
__global__ __launch_bounds__(256) void k_wselpv(
    const float* __restrict__ mdist, const float* __restrict__ scales,
    int sc_off, int Nq, int k_lo, float hw, float lw, float frac,
    const float* __restrict__ V, int Nk, float* __restrict__ out) {
  constexpr int CH = N / 256;              // float4 chunks per lane
  constexpr int SMAX = (CAP + 63) / 64;    // candidate slots per lane
  __shared__ float cv[4][CAP];
  __shared__ int ci[4][CAP];
  __shared__ int ccnt[4];
  __shared__ float svsel[4][2];

  int tid = threadIdx.x;
  int w = tid >> 6, l = tid & 63;
  int row = blockIdx.x * 4 + w;
  int h = row / Nq, j = row - h * Nq;
  float scale = scales[sc_off + h];
  const float4* mrow4 = (const float4*)(mdist + (size_t)row * N);

  // pass A: row min/max (streaming)
  float lmin = INFINITY, lmax = -INFINITY;
#pragma unroll
  for (int e = 0; e < CH; ++e) {
    float4 v = mrow4[l + 64 * e];
    lmin = fminf(lmin, fminf(fminf(v.x, v.y), fminf(v.z, v.w)));
    lmax = fmaxf(lmax, fmaxf(fmaxf(v.x, v.y), fmaxf(v.z, v.w)));
  }
#pragma unroll
  for (int off = 32; off > 0; off >>= 1) {
    lmin = fminf(lmin, __shfl_xor(lmin, off));
    lmax = fmaxf(lmax, __shfl_xor(lmax, off));
  }
  float rmin = lmin, rmax = lmax;

  int K = 0;
  float inv_total = 1.0f;
  if (rmax > rmin) {
    float range = rmax - rmin;
    float margin = fmaxf(fabsf(rmax) * 1e-6f, 1e-30f);
    float rtop = rmax + margin;
    float wtop = rmin + range * frac;
    if (!(wtop > rmin)) wtop = rtop;
    float v_lo = rmin, v_hi = rmin;
    int count = 0;
    for (int it = 0; it < 20; ++it) {
      if (l == 0) ccnt[w] = 0;
      // filter pass (row is L2-hot after pass A)
#pragma unroll
      for (int e = 0; e < CH; ++e) {
        float4 v = mrow4[l + 64 * e];
        int i0 = 4 * (l + 64 * e);
        if (v.x < wtop) { int p = atomicAdd(&ccnt[w], 1); if (p < CAP) { cv[w][p] = v.x; ci[w][p] = i0; } }
        if (v.y < wtop) { int p = atomicAdd(&ccnt[w], 1); if (p < CAP) { cv[w][p] = v.y; ci[w][p] = i0 + 1; } }
        if (v.z < wtop) { int p = atomicAdd(&ccnt[w], 1); if (p < CAP) { cv[w][p] = v.z; ci[w][p] = i0 + 2; } }
        if (v.w < wtop) { int p = atomicAdd(&ccnt[w], 1); if (p < CAP) { cv[w][p] = v.w; ci[w][p] = i0 + 3; } }
      }
      count = ccnt[w];
      if (count < k_lo + 2) { wtop = fminf(rmin + (wtop - rmin) * 3.0f, rtop); continue; }
      if (count > CAP)      { wtop = rmin + (wtop - rmin) * 0.6f; continue; }
      // counting selection for ranks k_lo, k_lo+1 among candidates
      float xv[SMAX]; int clt[SMAX], ceq[SMAX];
#pragma unroll
      for (int s = 0; s < SMAX; ++s) {
        int slot = l + 64 * s;
        xv[s] = (slot < count) ? cv[w][slot] : INFINITY;
        clt[s] = 0; ceq[s] = 0;
      }
      for (int jj = 0; jj < count; ++jj) {
        float y = cv[w][jj];
#pragma unroll
        for (int s = 0; s < SMAX; ++s) {
          clt[s] += (y < xv[s]) ? 1 : 0;
          ceq[s] += (y == xv[s]) ? 1 : 0;
        }
      }
#pragma unroll
      for (int s = 0; s < SMAX; ++s) {
        int slot = l + 64 * s;
        if (slot < count) {
          if (clt[s] <= k_lo && k_lo < clt[s] + ceq[s]) svsel[w][0] = xv[s];
          if (clt[s] <= k_lo + 1 && k_lo + 1 < clt[s] + ceq[s]) svsel[w][1] = xv[s];
        }
      }
      v_lo = svsel[w][0];
      v_hi = svsel[w][1];
      // guard: every non-candidate (>= wtop) must be excluded by thr
      float vlos0 = __fmul_rn(v_lo, scale);
      float vhis0 = __fmul_rn(v_hi, scale);
      float thr0 = __fadd_rn(__fmul_rn(vlos0, lw), __fmul_rn(vhis0, hw));
      if (__fmul_rn(wtop, scale) <= thr0) {
        wtop = fminf(rmin + (wtop - rmin) * 3.0f, rtop);
        continue;
      }
      break;
    }

    // threshold on rounded products (reference-exact formula)
    float vlos = __fmul_rn(v_lo, scale);
    float vhis = __fmul_rn(v_hi, scale);
    float thr = __fadd_rn(__fmul_rn(vlos, lw), __fmul_rn(vhis, hw));
    float rmins = __fmul_rn(rmin, scale);

    // read owned candidates (ALL reads before ANY writes), mark kept
    float ov[SMAX]; int oi[SMAX]; int kp[SMAX];
#pragma unroll
    for (int s = 0; s < SMAX; ++s) {
      int slot = l + 64 * s;
      ov[s] = 0.0f; oi[s] = 0; kp[s] = 0;
      if (slot < count) {
        ov[s] = cv[w][slot];
        oi[s] = ci[w][slot];
        kp[s] = (__fmul_rn(ov[s], scale) <= thr) ? 1 : 0;
      }
    }
    // ballot-compact kept in place; store unnormalized weights
    int base = 0;
    float lsum = 0.0f;
    unsigned long long mlt = (l == 0) ? 0ull : (~0ull >> (64 - l));
#pragma unroll
    for (int s = 0; s < SMAX; ++s) {
      unsigned long long bal = __ballot(kp[s] != 0);
      int pos = base + (int)__popcll(bal & mlt);
      if (kp[s]) {
        float e0 = expf(__fsub_rn(rmins, __fmul_rn(ov[s], scale)));
        cv[w][pos] = e0;
        ci[w][pos] = oi[s];
        lsum += e0;
      }
      base += (int)__popcll(bal);
    }
    K = base;
#pragma unroll
    for (int off = 32; off > 0; off >>= 1) lsum += __shfl_xor(lsum, off);
    inv_total = 1.0f / lsum;
  } else {
    K = 0;  // degenerate all-equal row: uniform weights over all Nk keys
    inv_total = 1.0f / (float)Nk;
  }

  // PV: lane covers (bh, c) and (bh+2, c); coalesced 128B per half-wave
  int bh = l >> 5, c = l & 31;
  int hcol = h * 32 + c;
  const float* Vb0 = V + (size_t)bh * Nk * 256;
  const float* Vb1 = V + (size_t)(bh + 2) * Nk * 256;
  float acc0 = 0.0f, acc1 = 0.0f;
  if (K > 0) {
    for (int e = 0; e < K; ++e) {
      float we = cv[w][e];
      int n = ci[w][e];
      size_t o = (size_t)n * 256 + hcol;
      acc0 = fmaf(we, Vb0[o], acc0);
      acc1 = fmaf(we, Vb1[o], acc1);
    }
  } else {
    for (int n = 0; n < Nk; ++n) {  // uniform fallback (never taken in practice)
      size_t o = (size_t)n * 256 + hcol;
      acc0 += Vb0[o];
      acc1 += Vb1[o];
    }
  }
  out[((size_t)bh * Nq + j) * 256 + hcol] = gelu_f(acc0 * inv_total);
  out[((size_t)(bh + 2) * Nq + j) * 256 + hcol] = gelu_f(acc1 * inv_total);
}

// ---------------- final 256->1 projection -----------------------------------
__global__ __launch_bounds__(256) void k_de2(const float* __restrict__ A,
                                             const float* __restrict__ w,
                                             const float* __restrict__ b,
                                             float* __restrict__ out) {
  int t = threadIdx.x;
  int row = blockIdx.x * 4 + (t >> 6);
  int lane = t & 63;
  const float* ar = A + (size_t)row * 256;
  float s = 0.0f;
  for (int i = lane; i < 256; i += 64) s = fmaf(ar[i], w[i], s);
#pragma unroll
  for (int off = 32; off > 0; off >>= 1) s += __shfl_down(s, off);
  if (lane == 0) out[row] = s + b[0];
}

// ---------------------------------------------------------------------------
struct SelParams { int k_lo; float hw, lw, frac; };
static SelParams sel_params(double q, int N) {
  SelParams p;
  float idx_q = (float)(q / 100.0);
  float pos = idx_q * (float)(N - 1);
  float lo = floorf(pos);
  p.k_lo = (int)lo;
  p.hw = pos - lo;
  p.lw = 1.0f - p.hw;
  float need = (float)(p.k_lo + 2);
  p.frac = (need + 6.0f * sqrtf(need) + 8.0f) / (float)N;
  return p;
}

extern "C" void kernel_launch(void* const* d_in, const int* in_sizes, int n_in,
                              void* d_out, int out_size, void* d_ws, size_t ws_size,
                              hipStream_t stream) {
  const float* x      = (const float*)d_in[0];
  const float* mdd    = (const float*)d_in[1];
  const float* mdb    = (const float*)d_in[2];
  const float* mdu    = (const float*)d_in[3];
  const float* en_w   = (const float*)d_in[4];
  const float* en_b   = (const float*)d_in[5];
  const float* down_r = (const float*)d_in[6];
  const float* down_w = (const float*)d_in[7];
  const float* pa_r   = (const float*)d_in[8];
  const float* pa_w   = (const float*)d_in[9];
  const float* mlp1_w = (const float*)d_in[10];
  const float* mlp1_b = (const float*)d_in[11];
  const float* mlp2_w = (const float*)d_in[12];
  const float* mlp2_b = (const float*)d_in[13];
  const float* res_w  = (const float*)d_in[14];
  const float* res_b  = (const float*)d_in[15];
  const float* up_r   = (const float*)d_in[16];
  const float* up_w   = (const float*)d_in[17];
  const float* de1_w  = (const float*)d_in[18];
  const float* de1_b  = (const float*)d_in[19];
  const float* de2_w  = (const float*)d_in[20];
  const float* de2_b  = (const float*)d_in[21];
  float* out = (float*)d_out;
  float* ws = (float*)d_ws;

  // ws layout (floats)
  float* hfull = ws;                     // 4194304
  float* val   = ws + 4194304;           // 4194304
  float* paout = ws + 8388608;           // 4194304
  float* hlat  = ws + 12582912;          // 1048576
  float* t1    = ws + 13631488;          // 1048576
  float* t2    = ws + 14680064;          // 1048576
  float* scales = ws + 15728640;         // 48

  k_scales<<<1, 64, 0, stream>>>(down_r, pa_r, up_r, scales);

  // encoder
  k_lift<<<16384, 256, 0, stream>>>(x, en_w, en_b, hfull);

  // down stage (H=8, Nq=1024, Nk=4096, q=3 -> keep ~124)
  SelParams pd = sel_params(3.0, 4096);
  k_linear<1, 0, 0><<<dim3(256, 4), 256, 0, stream>>>(hfull, down_w, nullptr, nullptr, val, 16384);
  k_wselpv<4096, 320><<<2048, 256, 0, stream>>>(mdd, scales, 0, 1024, pd.k_lo, pd.hw, pd.lw, pd.frac, val, 4096, hlat);

  // processor blocks (Nq=Nk=1024, q=5 -> keep ~53)
  SelParams pb = sel_params(5.0, 1024);
  for (int i = 0; i < 4; i++) {
    k_linear<1, 0, 0><<<dim3(64, 4), 256, 0, stream>>>(hlat, pa_w + (size_t)i * 65536, nullptr, nullptr, val, 4096);
    k_wselpv<1024, 256><<<2048, 256, 0, stream>>>(mdb + (size_t)i * 8388608, scales, 8 + i * 8, 1024, pb.k_lo, pb.hw, pb.lw, pb.frac, val, 1024, paout);
    k_linear<0, 1, 0><<<dim3(64, 4), 256, 0, stream>>>(paout, mlp1_w + (size_t)i * 65536, mlp1_b + i * 256, nullptr, t1, 4096);
    k_linear<0, 0, 0><<<dim3(64, 4), 256, 0, stream>>>(hlat, res_w + (size_t)i * 65536, res_b + i * 256, nullptr, t2, 4096);
    k_linear<0, 1, 1><<<dim3(64, 4), 256, 0, stream>>>(t1, mlp2_w + (size_t)i * 65536, mlp2_b + i * 256, t2, hlat, 4096);
  }

  // up stage (H=8, Nq=4096, Nk=1024, q=3 -> keep ~32)
  SelParams pu = sel_params(3.0, 1024);
  k_linear<1, 0, 0><<<dim3(64, 4), 256, 0, stream>>>(hlat, up_w, nullptr, nullptr, val, 4096);
  k_wselpv<1024, 192><<<8192, 256, 0, stream>>>(mdu, scales, 40, 4096, pu.k_lo, pu.hw, pu.lw, pu.frac, val, 1024, paout);

  // decoder
  k_linear<0, 1, 0><<<dim3(256, 4), 256, 0, stream>>>(paout, de1_w, de1_b, nullptr, hfull, 16384);
  k_de2<<<4096, 256, 0, stream>>>(hfull, de2_w, de2_b, out);
}

// Round 8
// 657.503 us; speedup vs baseline: 1.5149x; 1.2503x over previous
//
#include <hip/hip_runtime.h>
#include <math.h>

// ---------------------------------------------------------------------------
// PiT: encoder lift -> down pos-att -> 4x (pos-att + MLP + residual) -> up
// pos-att -> decoder. Sparse attention: wave-per-row window filter + counting
// selection (exact percentile), fused softmax+PV. Dense linears: split-bf16
// MFMA (hi+lo decomposition, 4 MFMA/product, f32 accumulate; rel err ~2^-18).
// ---------------------------------------------------------------------------

typedef short bf16x8 __attribute__((ext_vector_type(8)));
typedef float f32x4 __attribute__((ext_vector_type(4)));

__device__ __forceinline__ float gelu_f(float x) {
  float x3 = x * x * x;
  float inner = x + 0.044715f * x3;
  float t = tanhf(0.7978845608028654f * inner);
  return x * (0.5f * (1.0f + t));
}

__device__ __forceinline__ unsigned short f2bf(float x) {
  union { float f; unsigned u; } v; v.f = x;
  return (unsigned short)((v.u + 0x7fffu + ((v.u >> 16) & 1u)) >> 16);
}
__device__ __forceinline__ float bf2f(unsigned short b) {
  union { unsigned u; float f; } v; v.u = ((unsigned)b) << 16; return v.f;
}
__device__ __forceinline__ void store_bf(unsigned short* hi, unsigned short* lo,
                                         size_t i, float v) {
  unsigned short h = f2bf(v);
  hi[i] = h;
  lo[i] = f2bf(v - bf2f(h));
}

// ---------------- weight prep: f32 -> bf16 hi/lo (+ val-layout transpose) ---
struct PrepArgs {
  const float *mlp1, *mlp2, *res, *de1, *down, *pa, *up;
  unsigned short *rm_hi, *rm_lo, *val_hi, *val_lo;
};
__global__ __launch_bounds__(256) void k_prep(PrepArgs p) {
  int i = blockIdx.x * 256 + threadIdx.x;
  if (i < 851968) {
    const float* src; int off;
    if (i < 262144)      { src = p.mlp1; off = i; }
    else if (i < 524288) { src = p.mlp2; off = i - 262144; }
    else if (i < 786432) { src = p.res;  off = i - 524288; }
    else                 { src = p.de1;  off = i - 786432; }
    float x = src[off];
    store_bf(p.rm_hi, p.rm_lo, i, x);
  } else if (i < 1245184) {
    int ii = i - 851968;
    const float* src; int off;
    if (ii < 65536)       { src = p.down; off = ii; }
    else if (ii < 327680) { src = p.pa;   off = ii - 65536; }
    else                  { src = p.up;   off = ii - 327680; }
    int m = off >> 16, rem = off & 65535;
    int o = rem >> 8, j = rem & 255;  // dst row-major [o][j]
    float x = src[(size_t)m * 65536 + (o >> 5) * 8192 + j * 32 + (o & 31)];
    store_bf(p.val_hi, p.val_lo, ii, x);
  }
}

// ---------------- encoder lift: bf16 hi/lo output ---------------------------
__global__ __launch_bounds__(256) void k_lift(const float* __restrict__ x,
                                              const float* __restrict__ w,
                                              const float* __restrict__ b,
                                              unsigned short* __restrict__ ohi,
                                              unsigned short* __restrict__ olo) {
  int gid = blockIdx.x * 256 + threadIdx.x;
  int m = gid >> 8, o = gid & 255;
  float a0 = x[m * 3 + 0], a1 = x[m * 3 + 1], a2 = x[m * 3 + 2];
  float acc = a0 * w[o * 3 + 0] + a1 * w[o * 3 + 1] + a2 * w[o * 3 + 2] + b[o];
  store_bf(ohi, olo, gid, gelu_f(acc));
}

// ---------------- split-bf16 MFMA GEMM: C = act(A @ W'^T + bias [+ D]) ------
// A as hi/lo bf16 planes [M][256]; W' row-major [256 out][256 in] hi/lo.
// Verified gfx950 fragment mapping: A/B row = base+(l&15), k = (l>>4)*8+j;
// C/D col = l&15, row = (l>>4)*4 + reg.
template <int ACT, int ADDRES, int OBF16>
__global__ __launch_bounds__(256) void k_gemm(
    const unsigned short* __restrict__ Ahi, const unsigned short* __restrict__ Alo,
    const unsigned short* __restrict__ Whi, const unsigned short* __restrict__ Wlo,
    const float* __restrict__ bias, const float* __restrict__ D,
    float* __restrict__ C, unsigned short* __restrict__ Chi,
    unsigned short* __restrict__ Clo) {
  int t = threadIdx.x;
  int w = t >> 6, l = t & 63;
  int m0 = blockIdx.x * 64 + (w >> 1) * 32;
  int o0 = blockIdx.y * 64 + (w & 1) * 32;
  int fr = l & 15, fq = l >> 4;
  f32x4 acc[2][2] = {};
  size_t a0 = (size_t)(m0 + fr) * 256 + fq * 8;
  size_t a1 = a0 + 16 * 256;
  size_t b0 = (size_t)(o0 + fr) * 256 + fq * 8;
  size_t b1 = b0 + 16 * 256;
  for (int ks = 0; ks < 8; ++ks) {
    int k0 = ks * 32;
    bf16x8 A0h = *(const bf16x8*)(Ahi + a0 + k0);
    bf16x8 A0l = *(const bf16x8*)(Alo + a0 + k0);
    bf16x8 A1h = *(const bf16x8*)(Ahi + a1 + k0);
    bf16x8 A1l = *(const bf16x8*)(Alo + a1 + k0);
    bf16x8 B0h = *(const bf16x8*)(Whi + b0 + k0);
    bf16x8 B0l = *(const bf16x8*)(Wlo + b0 + k0);
    bf16x8 B1h = *(const bf16x8*)(Whi + b1 + k0);
    bf16x8 B1l = *(const bf16x8*)(Wlo + b1 + k0);
#define MFMA4(ACC, AH, AL, BH, BL)                                            \
  ACC = __builtin_amdgcn_mfma_f32_16x16x32_bf16(AH, BH, ACC, 0, 0, 0);        \
  ACC = __builtin_amdgcn_mfma_f32_16x16x32_bf16(AH, BL, ACC, 0, 0, 0);        \
  ACC = __builtin_amdgcn_mfma_f32_16x16x32_bf16(AL, BH, ACC, 0, 0, 0);        \
  ACC = __builtin_amdgcn_mfma_f32_16x16x32_bf16(AL, BL, ACC, 0, 0, 0);
    MFMA4(acc[0][0], A0h, A0l, B0h, B0l)
    MFMA4(acc[0][1], A0h, A0l, B1h, B1l)
    MFMA4(acc[1][0], A1h, A1l, B0h, B0l)
    MFMA4(acc[1][1], A1h, A1l, B1h, B1l)
#undef MFMA4
  }
  float bb[2];
  bb[0] = bias ? bias[o0 + fr] : 0.0f;
  bb[1] = bias ? bias[o0 + 16 + fr] : 0.0f;
#pragma unroll
  for (int i = 0; i < 2; ++i) {
#pragma unroll
    for (int jx = 0; jx < 2; ++jx) {
      int col = o0 + jx * 16 + fr;
#pragma unroll
      for (int r = 0; r < 4; ++r) {
        int rowi = m0 + i * 16 + fq * 4 + r;
        size_t oidx = (size_t)rowi * 256 + col;
        float v = acc[i][jx][r] + bb[jx];
        if (ADDRES) v += D[oidx];
        if (ACT) v = gelu_f(v);
        if (OBF16) store_bf(Chi, Clo, oidx, v);
        else C[oidx] = v;
      }
    }
  }
}

// ---------------- precompute the 48 attention scales ------------------------
__global__ void k_scales(const float* __restrict__ down_r,
                         const float* __restrict__ pa_r,
                         const float* __restrict__ up_r,
                         float* __restrict__ scales) {
  int t = threadIdx.x;
  if (t >= 48) return;
  float rv;
  if (t < 8) rv = down_r[t];
  else if (t < 40) rv = pa_r[t - 8];
  else rv = up_r[t - 40];
  double rd = (double)rv;
  float s1 = (float)sin(rd);
  float u = 1.0f + s1;
  float vc = (float)(0.7853981633974483 * (1.0 - 1e-7));
  float wf = vc * u;
  scales[t] = (float)tan((double)wf);
}

// ---------------- wave-per-row fused select + softmax + PV ------------------
// One 64-lane wave per (h, q-row); no __syncthreads (per-wave LDS slices,
// wave-internal LDS ops are in-order). Output written as bf16 hi/lo planes.
template <int N, int CAP>
__global__ __launch_bounds__(256) void k_wselpv(
    const float* __restrict__ mdist, const float* __restrict__ scales,
    int sc_off, int Nq, int k_lo, float hw, float lw, float frac,
    const float* __restrict__ V, int Nk,
    unsigned short* __restrict__ out_hi, unsigned short* __restrict__ out_lo) {
  constexpr int CH = N / 256;
  constexpr int SMAX = (CAP + 63) / 64;
  __shared__ float cv[4][CAP];
  __shared__ int ci[4][CAP];
  __shared__ int ccnt[4];
  __shared__ float svsel[4][2];

  int tid = threadIdx.x;
  int w = tid >> 6, l = tid & 63;
  int row = blockIdx.x * 4 + w;
  int h = row / Nq, j = row - h * Nq;
  float scale = scales[sc_off + h];
  const float4* mrow4 = (const float4*)(mdist + (size_t)row * N);

  float lmin = INFINITY, lmax = -INFINITY;
#pragma unroll
  for (int e = 0; e < CH; ++e) {
    float4 v = mrow4[l + 64 * e];
    lmin = fminf(lmin, fminf(fminf(v.x, v.y), fminf(v.z, v.w)));
    lmax = fmaxf(lmax, fmaxf(fmaxf(v.x, v.y), fmaxf(v.z, v.w)));
  }
#pragma unroll
  for (int off = 32; off > 0; off >>= 1) {
    lmin = fminf(lmin, __shfl_xor(lmin, off));
    lmax = fmaxf(lmax, __shfl_xor(lmax, off));
  }
  float rmin = lmin, rmax = lmax;

  int K = 0;
  float inv_total = 1.0f;
  if (rmax > rmin) {
    float range = rmax - rmin;
    float margin = fmaxf(fabsf(rmax) * 1e-6f, 1e-30f);
    float rtop = rmax + margin;
    float wtop = rmin + range * frac;
    if (!(wtop > rmin)) wtop = rtop;
    float v_lo = rmin, v_hi = rmin;
    int count = 0;
    for (int it = 0; it < 20; ++it) {
      if (l == 0) ccnt[w] = 0;
#pragma unroll
      for (int e = 0; e < CH; ++e) {
        float4 v = mrow4[l + 64 * e];
        int i0 = 4 * (l + 64 * e);
        if (v.x < wtop) { int p = atomicAdd(&ccnt[w], 1); if (p < CAP) { cv[w][p] = v.x; ci[w][p] = i0; } }
        if (v.y < wtop) { int p = atomicAdd(&ccnt[w], 1); if (p < CAP) { cv[w][p] = v.y; ci[w][p] = i0 + 1; } }
        if (v.z < wtop) { int p = atomicAdd(&ccnt[w], 1); if (p < CAP) { cv[w][p] = v.z; ci[w][p] = i0 + 2; } }
        if (v.w < wtop) { int p = atomicAdd(&ccnt[w], 1); if (p < CAP) { cv[w][p] = v.w; ci[w][p] = i0 + 3; } }
      }
      count = ccnt[w];
      if (count < k_lo + 2) { wtop = fminf(rmin + (wtop - rmin) * 3.0f, rtop); continue; }
      if (count > CAP)      { wtop = rmin + (wtop - rmin) * 0.6f; continue; }
      float xv[SMAX]; int clt[SMAX], ceq[SMAX];
#pragma unroll
      for (int s = 0; s < SMAX; ++s) {
        int slot = l + 64 * s;
        xv[s] = (slot < count) ? cv[w][slot] : INFINITY;
        clt[s] = 0; ceq[s] = 0;
      }
      for (int jj = 0; jj < count; ++jj) {
        float y = cv[w][jj];
#pragma unroll
        for (int s = 0; s < SMAX; ++s) {
          clt[s] += (y < xv[s]) ? 1 : 0;
          ceq[s] += (y == xv[s]) ? 1 : 0;
        }
      }
#pragma unroll
      for (int s = 0; s < SMAX; ++s) {
        int slot = l + 64 * s;
        if (slot < count) {
          if (clt[s] <= k_lo && k_lo < clt[s] + ceq[s]) svsel[w][0] = xv[s];
          if (clt[s] <= k_lo + 1 && k_lo + 1 < clt[s] + ceq[s]) svsel[w][1] = xv[s];
        }
      }
      v_lo = svsel[w][0];
      v_hi = svsel[w][1];
      float vlos0 = __fmul_rn(v_lo, scale);
      float vhis0 = __fmul_rn(v_hi, scale);
      float thr0 = __fadd_rn(__fmul_rn(vlos0, lw), __fmul_rn(vhis0, hw));
      if (__fmul_rn(wtop, scale) <= thr0) {
        wtop = fminf(rmin + (wtop - rmin) * 3.0f, rtop);
        continue;
      }
      break;
    }

    float vlos = __fmul_rn(v_lo, scale);
    float vhis = __fmul_rn(v_hi, scale);
    float thr = __fadd_rn(__fmul_rn(vlos, lw), __fmul_rn(vhis, hw));
    float rmins = __fmul_rn(rmin, scale);

    float ov[SMAX]; int oi[SMAX]; int kp[SMAX];
#pragma unroll
    for (int s = 0; s < SMAX; ++s) {
      int slot = l + 64 * s;
      ov[s] = 0.0f; oi[s] = 0; kp[s] = 0;
      if (slot < count) {
        ov[s] = cv[w][slot];
        oi[s] = ci[w][slot];
        kp[s] = (__fmul_rn(ov[s], scale) <= thr) ? 1 : 0;
      }
    }
    int base = 0;
    float lsum = 0.0f;
    unsigned long long mlt = (l == 0) ? 0ull : (~0ull >> (64 - l));
#pragma unroll
    for (int s = 0; s < SMAX; ++s) {
      unsigned long long bal = __ballot(kp[s] != 0);
      int pos = base + (int)__popcll(bal & mlt);
      if (kp[s]) {
        float e0 = expf(__fsub_rn(rmins, __fmul_rn(ov[s], scale)));
        cv[w][pos] = e0;
        ci[w][pos] = oi[s];
        lsum += e0;
      }
      base += (int)__popcll(bal);
    }
    K = base;
#pragma unroll
    for (int off = 32; off > 0; off >>= 1) lsum += __shfl_xor(lsum, off);
    inv_total = 1.0f / lsum;
  } else {
    K = 0;
    inv_total = 1.0f / (float)Nk;
  }

  int bh = l >> 5, c = l & 31;
  int hcol = h * 32 + c;
  const float* Vb0 = V + (size_t)bh * Nk * 256;
  const float* Vb1 = V + (size_t)(bh + 2) * Nk * 256;
  float acc0 = 0.0f, acc1 = 0.0f;
  if (K > 0) {
    for (int e = 0; e < K; ++e) {
      float we = cv[w][e];
      int n = ci[w][e];
      size_t o = (size_t)n * 256 + hcol;
      acc0 = fmaf(we, Vb0[o], acc0);
      acc1 = fmaf(we, Vb1[o], acc1);
    }
  } else {
    for (int n = 0; n < Nk; ++n) {
      size_t o = (size_t)n * 256 + hcol;
      acc0 += Vb0[o];
      acc1 += Vb1[o];
    }
  }
  size_t o0i = ((size_t)bh * Nq + j) * 256 + hcol;
  size_t o1i = ((size_t)(bh + 2) * Nq + j) * 256 + hcol;
  store_bf(out_hi, out_lo, o0i, gelu_f(acc0 * inv_total));
  store_bf(out_hi, out_lo, o1i, gelu_f(acc1 * inv_total));
}

// ---------------- final 256->1 projection -----------------------------------
__global__ __launch_bounds__(256) void k_de2(const float* __restrict__ A,
                                             const float* __restrict__ w,
                                             const float* __restrict__ b,
                                             float* __restrict__ out) {
  int t = threadIdx.x;
  int row = blockIdx.x * 4 + (t >> 6);
  int lane = t & 63;
  const float* ar = A + (size_t)row * 256;
  float s = 0.0f;
  for (int i = lane; i < 256; i += 64) s = fmaf(ar[i], w[i], s);
#pragma unroll
  for (int off = 32; off > 0; off >>= 1) s += __shfl_down(s, off);
  if (lane == 0) out[row] = s + b[0];
}

// ---------------------------------------------------------------------------
struct SelParams { int k_lo; float hw, lw, frac; };
static SelParams sel_params(double q, int N) {
  SelParams p;
  float idx_q = (float)(q / 100.0);
  float pos = idx_q * (float)(N - 1);
  float lo = floorf(pos);
  p.k_lo = (int)lo;
  p.hw = pos - lo;
  p.lw = 1.0f - p.hw;
  float need = (float)(p.k_lo + 2);
  p.frac = (need + 6.0f * sqrtf(need) + 8.0f) / (float)N;
  return p;
}

extern "C" void kernel_launch(void* const* d_in, const int* in_sizes, int n_in,
                              void* d_out, int out_size, void* d_ws, size_t ws_size,
                              hipStream_t stream) {
  const float* x      = (const float*)d_in[0];
  const float* mdd    = (const float*)d_in[1];
  const float* mdb    = (const float*)d_in[2];
  const float* mdu    = (const float*)d_in[3];
  const float* en_w   = (const float*)d_in[4];
  const float* en_b   = (const float*)d_in[5];
  const float* down_r = (const float*)d_in[6];
  const float* down_w = (const float*)d_in[7];
  const float* pa_r   = (const float*)d_in[8];
  const float* pa_w   = (const float*)d_in[9];
  const float* mlp1_w = (const float*)d_in[10];
  const float* mlp1_b = (const float*)d_in[11];
  const float* mlp2_w = (const float*)d_in[12];
  const float* mlp2_b = (const float*)d_in[13];
  const float* res_w  = (const float*)d_in[14];
  const float* res_b  = (const float*)d_in[15];
  const float* up_r   = (const float*)d_in[16];
  const float* up_w   = (const float*)d_in[17];
  const float* de1_w  = (const float*)d_in[18];
  const float* de1_b  = (const float*)d_in[19];
  const float* de2_w  = (const float*)d_in[20];
  const float* de2_b  = (const float*)d_in[21];
  float* out = (float*)d_out;
  char* base = (char*)d_ws;

  float* val               = (float*)base;                        // 16.78 MB (also de1 out)
  float* t2                = (float*)(base + 16777216);           // 4.19 MB
  unsigned short* hfull_hi = (unsigned short*)(base + 20971520);  // 8.39 MB
  unsigned short* hfull_lo = (unsigned short*)(base + 29360128);
  unsigned short* paout_hi = (unsigned short*)(base + 37748736);
  unsigned short* paout_lo = (unsigned short*)(base + 46137344);
  unsigned short* hlat_hi  = (unsigned short*)(base + 54525952);  // 2.10 MB
  unsigned short* hlat_lo  = (unsigned short*)(base + 56623104);
  unsigned short* t1_hi    = (unsigned short*)(base + 58720256);
  unsigned short* t1_lo    = (unsigned short*)(base + 60817408);
  unsigned short* wrm_hi   = (unsigned short*)(base + 62914560);  // 1.70 MB
  unsigned short* wrm_lo   = (unsigned short*)(base + 64618496);
  unsigned short* wval_hi  = (unsigned short*)(base + 66322432);  // 0.79 MB
  unsigned short* wval_lo  = (unsigned short*)(base + 67108864);
  float* scales            = (float*)(base + 67895296);

  k_scales<<<1, 64, 0, stream>>>(down_r, pa_r, up_r, scales);

  PrepArgs pa;
  pa.mlp1 = mlp1_w; pa.mlp2 = mlp2_w; pa.res = res_w; pa.de1 = de1_w;
  pa.down = down_w; pa.pa = pa_w; pa.up = up_w;
  pa.rm_hi = wrm_hi; pa.rm_lo = wrm_lo; pa.val_hi = wval_hi; pa.val_lo = wval_lo;
  k_prep<<<4864, 256, 0, stream>>>(pa);

  // encoder
  k_lift<<<16384, 256, 0, stream>>>(x, en_w, en_b, hfull_hi, hfull_lo);

  // down stage (H=8, Nq=1024, Nk=4096, q=3 -> keep ~124)
  SelParams pd = sel_params(3.0, 4096);
  k_gemm<0, 0, 0><<<dim3(256, 4), 256, 0, stream>>>(
      hfull_hi, hfull_lo, wval_hi, wval_lo, nullptr, nullptr, val, nullptr, nullptr);
  k_wselpv<4096, 256><<<2048, 256, 0, stream>>>(
      mdd, scales, 0, 1024, pd.k_lo, pd.hw, pd.lw, pd.frac, val, 4096, hlat_hi, hlat_lo);

  // processor blocks (Nq=Nk=1024, q=5 -> keep ~53)
  SelParams pb = sel_params(5.0, 1024);
  for (int i = 0; i < 4; i++) {
    k_gemm<0, 0, 0><<<dim3(64, 4), 256, 0, stream>>>(
        hlat_hi, hlat_lo, wval_hi + 65536 + i * 65536, wval_lo + 65536 + i * 65536,
        nullptr, nullptr, val, nullptr, nullptr);
    k_wselpv<1024, 256><<<2048, 256, 0, stream>>>(
        mdb + (size_t)i * 8388608, scales, 8 + i * 8, 1024, pb.k_lo, pb.hw, pb.lw,
        pb.frac, val, 1024, paout_hi, paout_lo);
    k_gemm<1, 0, 1><<<dim3(64, 4), 256, 0, stream>>>(
        paout_hi, paout_lo, wrm_hi + i * 65536, wrm_lo + i * 65536,
        mlp1_b + i * 256, nullptr, nullptr, t1_hi, t1_lo);
    k_gemm<0, 0, 0><<<dim3(64, 4), 256, 0, stream>>>(
        hlat_hi, hlat_lo, wrm_hi + 524288 + i * 65536, wrm_lo + 524288 + i * 65536,
        res_b + i * 256, nullptr, t2, nullptr, nullptr);
    k_gemm<1, 1, 1><<<dim3(64, 4), 256, 0, stream>>>(
        t1_hi, t1_lo, wrm_hi + 262144 + i * 65536, wrm_lo + 262144 + i * 65536,
        mlp2_b + i * 256, t2, nullptr, hlat_hi, hlat_lo);
  }

  // up stage (H=8, Nq=4096, Nk=1024, q=3 -> keep ~32)
  SelParams pu = sel_params(3.0, 1024);
  k_gemm<0, 0, 0><<<dim3(64, 4), 256, 0, stream>>>(
      hlat_hi, hlat_lo, wval_hi + 327680, wval_lo + 327680, nullptr, nullptr,
      val, nullptr, nullptr);
  k_wselpv<1024, 192><<<8192, 256, 0, stream>>>(
      mdu, scales, 40, 4096, pu.k_lo, pu.hw, pu.lw, pu.frac, val, 1024,
      paout_hi, paout_lo);

  // decoder
  k_gemm<1, 0, 0><<<dim3(256, 4), 256, 0, stream>>>(
      paout_hi, paout_lo, wrm_hi + 786432, wrm_lo + 786432, de1_b, nullptr,
      val, nullptr, nullptr);
  k_de2<<<4096, 256, 0, stream>>>(val, de2_w, de2_b, out);
}

// Round 9
// 548.717 us; speedup vs baseline: 1.8152x; 1.1983x over previous
//
#include <hip/hip_runtime.h>
#include <math.h>

// ---------------------------------------------------------------------------
// PiT: encoder lift -> down pos-att -> 4x (pos-att + MLP + residual) -> up
// pos-att -> decoder. Sparse attention: wave-per-row window filter + value-
// space bisection for exact percentile order stats, fused softmax+PV.
// Dense linears: split-bf16 MFMA (hi+lo, 4 MFMA/product, f32 accumulate).
// ---------------------------------------------------------------------------

typedef short bf16x8 __attribute__((ext_vector_type(8)));
typedef float f32x4 __attribute__((ext_vector_type(4)));

__device__ __forceinline__ float gelu_f(float x) {
  float x3 = x * x * x;
  float inner = x + 0.044715f * x3;
  float t = tanhf(0.7978845608028654f * inner);
  return x * (0.5f * (1.0f + t));
}

__device__ __forceinline__ unsigned short f2bf(float x) {
  union { float f; unsigned u; } v; v.f = x;
  return (unsigned short)((v.u + 0x7fffu + ((v.u >> 16) & 1u)) >> 16);
}
__device__ __forceinline__ float bf2f(unsigned short b) {
  union { unsigned u; float f; } v; v.u = ((unsigned)b) << 16; return v.f;
}
__device__ __forceinline__ void store_bf(unsigned short* hi, unsigned short* lo,
                                         size_t i, float v) {
  unsigned short h = f2bf(v);
  hi[i] = h;
  lo[i] = f2bf(v - bf2f(h));
}

// ---------------- weight prep: f32 -> bf16 hi/lo (+ val-layout transpose) ---
struct PrepArgs {
  const float *mlp1, *mlp2, *res, *de1, *down, *pa, *up;
  unsigned short *rm_hi, *rm_lo, *val_hi, *val_lo;
};
__global__ __launch_bounds__(256) void k_prep(PrepArgs p) {
  int i = blockIdx.x * 256 + threadIdx.x;
  if (i < 851968) {
    const float* src; int off;
    if (i < 262144)      { src = p.mlp1; off = i; }
    else if (i < 524288) { src = p.mlp2; off = i - 262144; }
    else if (i < 786432) { src = p.res;  off = i - 524288; }
    else                 { src = p.de1;  off = i - 786432; }
    float x = src[off];
    store_bf(p.rm_hi, p.rm_lo, i, x);
  } else if (i < 1245184) {
    int ii = i - 851968;
    const float* src; int off;
    if (ii < 65536)       { src = p.down; off = ii; }
    else if (ii < 327680) { src = p.pa;   off = ii - 65536; }
    else                  { src = p.up;   off = ii - 327680; }
    int m = off >> 16, rem = off & 65535;
    int o = rem >> 8, j = rem & 255;  // dst row-major [o][j]
    float x = src[(size_t)m * 65536 + (o >> 5) * 8192 + j * 32 + (o & 31)];
    store_bf(p.val_hi, p.val_lo, ii, x);
  }
}

// ---------------- encoder lift: bf16 hi/lo output ---------------------------
__global__ __launch_bounds__(256) void k_lift(const float* __restrict__ x,
                                              const float* __restrict__ w,
                                              const float* __restrict__ b,
                                              unsigned short* __restrict__ ohi,
                                              unsigned short* __restrict__ olo) {
  int gid = blockIdx.x * 256 + threadIdx.x;
  int m = gid >> 8, o = gid & 255;
  float a0 = x[m * 3 + 0], a1 = x[m * 3 + 1], a2 = x[m * 3 + 2];
  float acc = a0 * w[o * 3 + 0] + a1 * w[o * 3 + 1] + a2 * w[o * 3 + 2] + b[o];
  store_bf(ohi, olo, gid, gelu_f(acc));
}

// ---------------- split-bf16 MFMA GEMM: C = act(A @ W'^T + bias [+ D]) ------
template <int ACT, int ADDRES, int OBF16>
__global__ __launch_bounds__(256) void k_gemm(
    const unsigned short* __restrict__ Ahi, const unsigned short* __restrict__ Alo,
    const unsigned short* __restrict__ Whi, const unsigned short* __restrict__ Wlo,
    const float* __restrict__ bias, const float* __restrict__ D,
    float* __restrict__ C, unsigned short* __restrict__ Chi,
    unsigned short* __restrict__ Clo) {
  int t = threadIdx.x;
  int w = t >> 6, l = t & 63;
  int m0 = blockIdx.x * 64 + (w >> 1) * 32;
  int o0 = blockIdx.y * 64 + (w & 1) * 32;
  int fr = l & 15, fq = l >> 4;
  f32x4 acc[2][2] = {};
  size_t a0 = (size_t)(m0 + fr) * 256 + fq * 8;
  size_t a1 = a0 + 16 * 256;
  size_t b0 = (size_t)(o0 + fr) * 256 + fq * 8;
  size_t b1 = b0 + 16 * 256;
  for (int ks = 0; ks < 8; ++ks) {
    int k0 = ks * 32;
    bf16x8 A0h = *(const bf16x8*)(Ahi + a0 + k0);
    bf16x8 A0l = *(const bf16x8*)(Alo + a0 + k0);
    bf16x8 A1h = *(const bf16x8*)(Ahi + a1 + k0);
    bf16x8 A1l = *(const bf16x8*)(Alo + a1 + k0);
    bf16x8 B0h = *(const bf16x8*)(Whi + b0 + k0);
    bf16x8 B0l = *(const bf16x8*)(Wlo + b0 + k0);
    bf16x8 B1h = *(const bf16x8*)(Whi + b1 + k0);
    bf16x8 B1l = *(const bf16x8*)(Wlo + b1 + k0);
#define MFMA4(ACC, AH, AL, BH, BL)                                            \
  ACC = __builtin_amdgcn_mfma_f32_16x16x32_bf16(AH, BH, ACC, 0, 0, 0);        \
  ACC = __builtin_amdgcn_mfma_f32_16x16x32_bf16(AH, BL, ACC, 0, 0, 0);        \
  ACC = __builtin_amdgcn_mfma_f32_16x16x32_bf16(AL, BH, ACC, 0, 0, 0);        \
  ACC = __builtin_amdgcn_mfma_f32_16x16x32_bf16(AL, BL, ACC, 0, 0, 0);
    MFMA4(acc[0][0], A0h, A0l, B0h, B0l)
    MFMA4(acc[0][1], A0h, A0l, B1h, B1l)
    MFMA4(acc[1][0], A1h, A1l, B0h, B0l)
    MFMA4(acc[1][1], A1h, A1l, B1h, B1l)
#undef MFMA4
  }
  float bb[2];
  bb[0] = bias ? bias[o0 + fr] : 0.0f;
  bb[1] = bias ? bias[o0 + 16 + fr] : 0.0f;
#pragma unroll
  for (int i = 0; i < 2; ++i) {
#pragma unroll
    for (int jx = 0; jx < 2; ++jx) {
      int col = o0 + jx * 16 + fr;
#pragma unroll
      for (int r = 0; r < 4; ++r) {
        int rowi = m0 + i * 16 + fq * 4 + r;
        size_t oidx = (size_t)rowi * 256 + col;
        float v = acc[i][jx][r] + bb[jx];
        if (ADDRES) v += D[oidx];
        if (ACT) v = gelu_f(v);
        if (OBF16) store_bf(Chi, Clo, oidx, v);
        else C[oidx] = v;
      }
    }
  }
}

// ---------------- precompute the 48 attention scales ------------------------
__global__ void k_scales(const float* __restrict__ down_r,
                         const float* __restrict__ pa_r,
                         const float* __restrict__ up_r,
                         float* __restrict__ scales) {
  int t = threadIdx.x;
  if (t >= 48) return;
  float rv;
  if (t < 8) rv = down_r[t];
  else if (t < 40) rv = pa_r[t - 8];
  else rv = up_r[t - 40];
  double rd = (double)rv;
  float s1 = (float)sin(rd);
  float u = 1.0f + s1;
  float vc = (float)(0.7853981633974483 * (1.0 - 1e-7));
  float wf = vc * u;
  scales[t] = (float)tan((double)wf);
}

// ---------------- wave-per-row fused select + softmax + PV ------------------
// One 64-lane wave per (h, q-row); no __syncthreads. Window filter -> LDS
// candidates; exact order stats k_lo,k_lo+1 via value-space BISECTION over
// register-held candidates (window invariant: always contains both ranks).
// Straddle exit gives max-of-lower/min-of-upper (tie-safe); small windows go
// through a tiny counting select; degenerate windows fall back to full
// counting (exactness on any data). Threshold on f32-rounded products =
// reference-exact semantics.
template <int N, int CAP>
__global__ __launch_bounds__(256) void k_wselpv(
    const float* __restrict__ mdist, const float* __restrict__ scales,
    int sc_off, int Nq, int k_lo, float hw, float lw, float frac,
    const float* __restrict__ V, int Nk,
    unsigned short* __restrict__ out_hi, unsigned short* __restrict__ out_lo) {
  constexpr int CH = N / 256;
  constexpr int SMAX = (CAP + 63) / 64;
  __shared__ float cv[4][CAP];
  __shared__ int ci[4][CAP];
  __shared__ int ccnt[4];
  __shared__ float svsel[4][2];
  __shared__ float swin[4][32];

  int tid = threadIdx.x;
  int w = tid >> 6, l = tid & 63;
  int row = blockIdx.x * 4 + w;
  int h = row / Nq, j = row - h * Nq;
  float scale = scales[sc_off + h];
  const float4* mrow4 = (const float4*)(mdist + (size_t)row * N);

  // pass A: row min/max
  float lmin = INFINITY, lmax = -INFINITY;
#pragma unroll
  for (int e = 0; e < CH; ++e) {
    float4 v = mrow4[l + 64 * e];
    lmin = fminf(lmin, fminf(fminf(v.x, v.y), fminf(v.z, v.w)));
    lmax = fmaxf(lmax, fmaxf(fmaxf(v.x, v.y), fmaxf(v.z, v.w)));
  }
#pragma unroll
  for (int off = 32; off > 0; off >>= 1) {
    lmin = fminf(lmin, __shfl_xor(lmin, off));
    lmax = fmaxf(lmax, __shfl_xor(lmax, off));
  }
  float rmin = lmin, rmax = lmax;

  int K = 0;
  float inv_total = 1.0f;
  if (rmax > rmin) {
    float range = rmax - rmin;
    float margin = fmaxf(fabsf(rmax) * 1e-6f, 1e-30f);
    float rtop = rmax + margin;
    float wtop = rmin + range * frac;
    if (!(wtop > rmin)) wtop = rtop;
    float v_lo = rmin, v_hi = rmin;
    int count = 0;
    float xv[SMAX];
    for (int it = 0; it < 20; ++it) {
      if (l == 0) ccnt[w] = 0;
      // filter pass (row L2-hot after pass A)
#pragma unroll
      for (int e = 0; e < CH; ++e) {
        float4 v = mrow4[l + 64 * e];
        int i0 = 4 * (l + 64 * e);
        if (v.x < wtop) { int p = atomicAdd(&ccnt[w], 1); if (p < CAP) { cv[w][p] = v.x; ci[w][p] = i0; } }
        if (v.y < wtop) { int p = atomicAdd(&ccnt[w], 1); if (p < CAP) { cv[w][p] = v.y; ci[w][p] = i0 + 1; } }
        if (v.z < wtop) { int p = atomicAdd(&ccnt[w], 1); if (p < CAP) { cv[w][p] = v.z; ci[w][p] = i0 + 2; } }
        if (v.w < wtop) { int p = atomicAdd(&ccnt[w], 1); if (p < CAP) { cv[w][p] = v.w; ci[w][p] = i0 + 3; } }
      }
      count = ccnt[w];
      if (count < k_lo + 2) { wtop = fminf(rmin + (wtop - rmin) * 3.0f, rtop); continue; }
      if (count > CAP)      { wtop = rmin + (wtop - rmin) * 0.6f; continue; }

      // candidates into regs
#pragma unroll
      for (int s = 0; s < SMAX; ++s) {
        int slot = l + 64 * s;
        xv[s] = (slot < count) ? cv[w][slot] : INFINITY;
      }
      // ---- value-space bisection; window always holds ranks k_lo, k_lo+1 ---
      float wlo = rmin, whi = wtop;
      int rbase = 0, cntw = count;
      int found = 0, degen = 0;
      for (int bs = 0; bs < 32; ++bs) {
        if (cntw <= 24) break;
        float mid = 0.5f * (wlo + whi);
        if (!(mid > wlo && mid < whi)) { degen = 1; break; }
        int c4 = 0;
#pragma unroll
        for (int s = 0; s < SMAX; ++s) c4 += (xv[s] >= wlo && xv[s] < mid) ? 1 : 0;
#pragma unroll
        for (int off = 32; off > 0; off >>= 1) c4 += __shfl_xor(c4, off);
        int rrel = k_lo - rbase;
        if (rrel + 1 < c4) { whi = mid; cntw = c4; }
        else if (rrel >= c4) { wlo = mid; rbase += c4; cntw -= c4; }
        else {
          // straddle: rank k_lo = max of lower half, k_lo+1 = min of upper
          float mx = -INFINITY, mn = INFINITY;
#pragma unroll
          for (int s = 0; s < SMAX; ++s) {
            float v = xv[s];
            if (v >= wlo && v < mid) mx = fmaxf(mx, v);
            if (v >= mid && v < whi) mn = fminf(mn, v);
          }
#pragma unroll
          for (int off = 32; off > 0; off >>= 1) {
            mx = fmaxf(mx, __shfl_xor(mx, off));
            mn = fminf(mn, __shfl_xor(mn, off));
          }
          v_lo = mx; v_hi = mn; found = 1;
          break;
        }
      }
      if (!found) {
        if (!degen && cntw <= 32) {
          // gather in-window candidates into tiny list, counting-select
          if (l == 0) ccnt[w] = 0;
#pragma unroll
          for (int s = 0; s < SMAX; ++s) {
            float v = xv[s];
            if (v >= wlo && v < whi) {
              int p = atomicAdd(&ccnt[w], 1);
              if (p < 32) swin[w][p] = v;
            }
          }
          int m = ccnt[w];
          if (m > 32) m = 32;
          float myv = (l < m) ? swin[w][l] : INFINITY;
          int clt = 0, ceq = 0;
          for (int jj = 0; jj < m; ++jj) {
            float y = swin[w][jj];
            clt += (y < myv) ? 1 : 0;
            ceq += (y == myv) ? 1 : 0;
          }
          int rr = k_lo - rbase;
          if (l < m) {
            if (clt <= rr && rr < clt + ceq) svsel[w][0] = myv;
            if (clt <= rr + 1 && rr + 1 < clt + ceq) svsel[w][1] = myv;
          }
          v_lo = svsel[w][0];
          v_hi = svsel[w][1];
        } else {
          // full counting selection over all candidates (exact fallback)
          int clt[SMAX], ceq[SMAX];
#pragma unroll
          for (int s = 0; s < SMAX; ++s) { clt[s] = 0; ceq[s] = 0; }
          for (int jj = 0; jj < count; ++jj) {
            float y = cv[w][jj];
#pragma unroll
            for (int s = 0; s < SMAX; ++s) {
              clt[s] += (y < xv[s]) ? 1 : 0;
              ceq[s] += (y == xv[s]) ? 1 : 0;
            }
          }
#pragma unroll
          for (int s = 0; s < SMAX; ++s) {
            int slot = l + 64 * s;
            if (slot < count) {
              if (clt[s] <= k_lo && k_lo < clt[s] + ceq[s]) svsel[w][0] = xv[s];
              if (clt[s] <= k_lo + 1 && k_lo + 1 < clt[s] + ceq[s]) svsel[w][1] = xv[s];
            }
          }
          v_lo = svsel[w][0];
          v_hi = svsel[w][1];
        }
      }
      // guard: every non-candidate (>= wtop) must be excluded by thr
      float vlos0 = __fmul_rn(v_lo, scale);
      float vhis0 = __fmul_rn(v_hi, scale);
      float thr0 = __fadd_rn(__fmul_rn(vlos0, lw), __fmul_rn(vhis0, hw));
      if (__fmul_rn(wtop, scale) <= thr0) {
        wtop = fminf(rmin + (wtop - rmin) * 3.0f, rtop);
        continue;
      }
      break;
    }

    float vlos = __fmul_rn(v_lo, scale);
    float vhis = __fmul_rn(v_hi, scale);
    float thr = __fadd_rn(__fmul_rn(vlos, lw), __fmul_rn(vhis, hw));
    float rmins = __fmul_rn(rmin, scale);

    // kept = candidates with rn(v*scale) <= thr; values already in xv regs
    int oi[SMAX]; int kp[SMAX];
#pragma unroll
    for (int s = 0; s < SMAX; ++s) {
      int slot = l + 64 * s;
      oi[s] = 0; kp[s] = 0;
      if (slot < count) {
        oi[s] = ci[w][slot];
        kp[s] = (__fmul_rn(xv[s], scale) <= thr) ? 1 : 0;
      }
    }
    int base = 0;
    float lsum = 0.0f;
    unsigned long long mlt = (l == 0) ? 0ull : (~0ull >> (64 - l));
#pragma unroll
    for (int s = 0; s < SMAX; ++s) {
      unsigned long long bal = __ballot(kp[s] != 0);
      int pos = base + (int)__popcll(bal & mlt);
      if (kp[s]) {
        float e0 = expf(__fsub_rn(rmins, __fmul_rn(xv[s], scale)));
        cv[w][pos] = e0;
        ci[w][pos] = oi[s];
        lsum += e0;
      }
      base += (int)__popcll(bal);
    }
    K = base;
#pragma unroll
    for (int off = 32; off > 0; off >>= 1) lsum += __shfl_xor(lsum, off);
    inv_total = 1.0f / lsum;
  } else {
    K = 0;
    inv_total = 1.0f / (float)Nk;
  }

  // PV: lane covers (bh, c) and (bh+2, c)
  int bh = l >> 5, c = l & 31;
  int hcol = h * 32 + c;
  const float* Vb0 = V + (size_t)bh * Nk * 256;
  const float* Vb1 = V + (size_t)(bh + 2) * Nk * 256;
  float acc0 = 0.0f, acc1 = 0.0f;
  if (K > 0) {
    for (int e = 0; e < K; ++e) {
      float we = cv[w][e];
      int n = ci[w][e];
      size_t o = (size_t)n * 256 + hcol;
      acc0 = fmaf(we, Vb0[o], acc0);
      acc1 = fmaf(we, Vb1[o], acc1);
    }
  } else {
    for (int n = 0; n < Nk; ++n) {
      size_t o = (size_t)n * 256 + hcol;
      acc0 += Vb0[o];
      acc1 += Vb1[o];
    }
  }
  size_t o0i = ((size_t)bh * Nq + j) * 256 + hcol;
  size_t o1i = ((size_t)(bh + 2) * Nq + j) * 256 + hcol;
  store_bf(out_hi, out_lo, o0i, gelu_f(acc0 * inv_total));
  store_bf(out_hi, out_lo, o1i, gelu_f(acc1 * inv_total));
}

// ---------------- final 256->1 projection -----------------------------------
__global__ __launch_bounds__(256) void k_de2(const float* __restrict__ A,
                                             const float* __restrict__ w,
                                             const float* __restrict__ b,
                                             float* __restrict__ out) {
  int t = threadIdx.x;
  int row = blockIdx.x * 4 + (t >> 6);
  int lane = t & 63;
  const float* ar = A + (size_t)row * 256;
  float s = 0.0f;
  for (int i = lane; i < 256; i += 64) s = fmaf(ar[i], w[i], s);
#pragma unroll
  for (int off = 32; off > 0; off >>= 1) s += __shfl_down(s, off);
  if (lane == 0) out[row] = s + b[0];
}

// ---------------------------------------------------------------------------
struct SelParams { int k_lo; float hw, lw, frac; };
static SelParams sel_params(double q, int N) {
  SelParams p;
  float idx_q = (float)(q / 100.0);
  float pos = idx_q * (float)(N - 1);
  float lo = floorf(pos);
  p.k_lo = (int)lo;
  p.hw = pos - lo;
  p.lw = 1.0f - p.hw;
  float need = (float)(p.k_lo + 2);
  p.frac = (need + 6.0f * sqrtf(need) + 8.0f) / (float)N;
  return p;
}

extern "C" void kernel_launch(void* const* d_in, const int* in_sizes, int n_in,
                              void* d_out, int out_size, void* d_ws, size_t ws_size,
                              hipStream_t stream) {
  const float* x      = (const float*)d_in[0];
  const float* mdd    = (const float*)d_in[1];
  const float* mdb    = (const float*)d_in[2];
  const float* mdu    = (const float*)d_in[3];
  const float* en_w   = (const float*)d_in[4];
  const float* en_b   = (const float*)d_in[5];
  const float* down_r = (const float*)d_in[6];
  const float* down_w = (const float*)d_in[7];
  const float* pa_r   = (const float*)d_in[8];
  const float* pa_w   = (const float*)d_in[9];
  const float* mlp1_w = (const float*)d_in[10];
  const float* mlp1_b = (const float*)d_in[11];
  const float* mlp2_w = (const float*)d_in[12];
  const float* mlp2_b = (const float*)d_in[13];
  const float* res_w  = (const float*)d_in[14];
  const float* res_b  = (const float*)d_in[15];
  const float* up_r   = (const float*)d_in[16];
  const float* up_w   = (const float*)d_in[17];
  const float* de1_w  = (const float*)d_in[18];
  const float* de1_b  = (const float*)d_in[19];
  const float* de2_w  = (const float*)d_in[20];
  const float* de2_b  = (const float*)d_in[21];
  float* out = (float*)d_out;
  char* base = (char*)d_ws;

  float* val               = (float*)base;                        // 16.78 MB (also de1 out)
  float* t2                = (float*)(base + 16777216);           // 4.19 MB
  unsigned short* hfull_hi = (unsigned short*)(base + 20971520);  // 8.39 MB
  unsigned short* hfull_lo = (unsigned short*)(base + 29360128);
  unsigned short* paout_hi = (unsigned short*)(base + 37748736);
  unsigned short* paout_lo = (unsigned short*)(base + 46137344);
  unsigned short* hlat_hi  = (unsigned short*)(base + 54525952);  // 2.10 MB
  unsigned short* hlat_lo  = (unsigned short*)(base + 56623104);
  unsigned short* t1_hi    = (unsigned short*)(base + 58720256);
  unsigned short* t1_lo    = (unsigned short*)(base + 60817408);
  unsigned short* wrm_hi   = (unsigned short*)(base + 62914560);  // 1.70 MB
  unsigned short* wrm_lo   = (unsigned short*)(base + 64618496);
  unsigned short* wval_hi  = (unsigned short*)(base + 66322432);  // 0.79 MB
  unsigned short* wval_lo  = (unsigned short*)(base + 67108864);
  float* scales            = (float*)(base + 67895296);

  k_scales<<<1, 64, 0, stream>>>(down_r, pa_r, up_r, scales);

  PrepArgs pa;
  pa.mlp1 = mlp1_w; pa.mlp2 = mlp2_w; pa.res = res_w; pa.de1 = de1_w;
  pa.down = down_w; pa.pa = pa_w; pa.up = up_w;
  pa.rm_hi = wrm_hi; pa.rm_lo = wrm_lo; pa.val_hi = wval_hi; pa.val_lo = wval_lo;
  k_prep<<<4864, 256, 0, stream>>>(pa);

  // encoder
  k_lift<<<16384, 256, 0, stream>>>(x, en_w, en_b, hfull_hi, hfull_lo);

  // down stage (H=8, Nq=1024, Nk=4096, q=3 -> keep ~124)
  SelParams pd = sel_params(3.0, 4096);
  k_gemm<0, 0, 0><<<dim3(256, 4), 256, 0, stream>>>(
      hfull_hi, hfull_lo, wval_hi, wval_lo, nullptr, nullptr, val, nullptr, nullptr);
  k_wselpv<4096, 256><<<2048, 256, 0, stream>>>(
      mdd, scales, 0, 1024, pd.k_lo, pd.hw, pd.lw, pd.frac, val, 4096, hlat_hi, hlat_lo);

  // processor blocks (Nq=Nk=1024, q=5 -> keep ~53)
  SelParams pb = sel_params(5.0, 1024);
  for (int i = 0; i < 4; i++) {
    k_gemm<0, 0, 0><<<dim3(64, 4), 256, 0, stream>>>(
        hlat_hi, hlat_lo, wval_hi + 65536 + i * 65536, wval_lo + 65536 + i * 65536,
        nullptr, nullptr, val, nullptr, nullptr);
    k_wselpv<1024, 256><<<2048, 256, 0, stream>>>(
        mdb + (size_t)i * 8388608, scales, 8 + i * 8, 1024, pb.k_lo, pb.hw, pb.lw,
        pb.frac, val, 1024, paout_hi, paout_lo);
    k_gemm<1, 0, 1><<<dim3(64, 4), 256, 0, stream>>>(
        paout_hi, paout_lo, wrm_hi + i * 65536, wrm_lo + i * 65536,
        mlp1_b + i * 256, nullptr, nullptr, t1_hi, t1_lo);
    k_gemm<0, 0, 0><<<dim3(64, 4), 256, 0, stream>>>(
        hlat_hi, hlat_lo, wrm_hi + 524288 + i * 65536, wrm_lo + 524288 + i * 65536,
        res_b + i * 256, nullptr, t2, nullptr, nullptr);
    k_gemm<1, 1, 1><<<dim3(64, 4), 256, 0, stream>>>(
        t1_hi, t1_lo, wrm_hi + 262144 + i * 65536, wrm_lo + 262144 + i * 65536,
        mlp2_b + i * 256, t2, nullptr, hlat_hi, hlat_lo);
  }

  // up stage (H=8, Nq=4096, Nk=1024, q=3 -> keep ~32)
  SelParams pu = sel_params(3.0, 1024);
  k_gemm<0, 0, 0><<<dim3(64, 4), 256, 0, stream>>>(
      hlat_hi, hlat_lo, wval_hi + 327680, wval_lo + 327680, nullptr, nullptr,
      val, nullptr, nullptr);
  k_wselpv<1024, 192><<<8192, 256, 0, stream>>>(
      mdu, scales, 40, 4096, pu.k_lo, pu.hw, pu.lw, pu.frac, val, 1024,
      paout_hi, paout_lo);

  // decoder
  k_gemm<1, 0, 0><<<dim3(256, 4), 256, 0, stream>>>(
      paout_hi, paout_lo, wrm_hi + 786432, wrm_lo + 786432, de1_b, nullptr,
      val, nullptr, nullptr);
  k_de2<<<4096, 256, 0, stream>>>(val, de2_w, de2_b, out);
}